// Round 4
// baseline (1233.406 us; speedup 1.0000x reference)
//
#include <hip/hip_runtime.h>
#include <math.h>

#define Bsz 512
#define Tsz 512
#define Hd 64

typedef float v2f __attribute__((ext_vector_type(2)));

__device__ __forceinline__ float fsig(float x){ return 1.0f/(1.0f+__expf(-x)); }
__device__ __forceinline__ float ftanh(float x){
    float ax=fabsf(x); float e=__expf(-2.0f*ax);
    float t=(1.0f-e)/(1.0f+e); return copysignf(t,x);
}
__device__ __forceinline__ float rlane(float v, int k){
    return __int_as_float(__builtin_amdgcn_readlane(__float_as_int(v), k));
}

// 4 waves per batch row:
//   w0/w1 producers: pre-gates from x (rows w*128+lane, w*128+64+lane) -> LDS ring (depth 4)
//   w2/w3 consumers: recurrent matvec for the same row pairs. h is broadcast via
//       64 v_readlane -> SGPRs (per-SIMD VALU pipe, zero LDS datapath), weights in VGPRs.
//   Gate halves cross between consumer waves through a parity LDS buffer; both
//   consumers redundantly finish c/h (identical values). One __syncthreads per step,
//   in SEPARATE producer/consumer loops with matched barrier counts (so regalloc
//   is max(arms), not union -> no spill).
//
// Consumer pipeline at step s:  finish h(s-3)  ->  matvec+pregate for t=s-2.
// ring[t] written by producers at step t (2 steps of slack); exch written at s, read s+1.

template<int FINQ, bool STORE_H, bool DO_FC>
__global__ __launch_bounds__(256, 2)
void lstm_layer(const float* __restrict__ xin,    // [B, T, FINQ*4]
                const float4* __restrict__ Wih4,  // [256, FINQ]
                const float4* __restrict__ Whh4,  // [256, 16]
                const float* __restrict__ bih,
                const float* __restrict__ bhh,
                float* __restrict__ hout,         // [B, T, 64] (STORE_H)
                const float* __restrict__ fcW,
                const float* __restrict__ fcb,
                float* __restrict__ out)          // [B] (DO_FC)
{
    __shared__ float2 ring[4][128];  // [depth][pairIdx]: pairIdx = u*64+lane -> rows (u*128+l, u*128+64+l)
    __shared__ float2 exch[2][128];  // [parity][pairIdx]: pre-act gate pairs crossing consumer waves

    const int tid  = threadIdx.x;
    const int lane = tid & 63;
    const int wv   = tid >> 6;
    const int b    = blockIdx.x;

    if (wv < 2) {
        // ---------------- producer ----------------
        const int u  = wv;
        const int rA = u * 128 + lane;        // gate rows (i,f) for u=0, (g,o) for u=1
        const int rB = u * 128 + 64 + lane;
        float4 wA[FINQ], wB[FINQ];
        #pragma unroll
        for (int q = 0; q < FINQ; ++q) wA[q] = Wih4[rA * FINQ + q];
        #pragma unroll
        for (int q = 0; q < FINQ; ++q) wB[q] = Wih4[rB * FINQ + q];
        const float bA = bih[rA] + bhh[rA];
        const float bB = bih[rB] + bhh[rB];

        const float4* xg = (const float4*)(xin + (size_t)b * Tsz * (FINQ * 4));
        float4 cur[FINQ], nxt[FINQ];
        #pragma unroll
        for (int q = 0; q < FINQ; ++q) cur[q] = xg[q];   // t=0 (wave-uniform address)

        #pragma unroll 1
        for (int s = 0; s < Tsz + 3; ++s) {
            if (s < Tsz) {
                if (s + 1 < Tsz) {
                    #pragma unroll
                    for (int q = 0; q < FINQ; ++q) nxt[q] = xg[(s + 1) * FINQ + q];
                }
                v2f aA0 = {bA, 0.f}, aA1 = {0.f, 0.f};
                v2f aB0 = {bB, 0.f}, aB1 = {0.f, 0.f};
                #pragma unroll
                for (int q = 0; q < FINQ; ++q) {
                    v2f xu = {cur[q].x, cur[q].y};
                    v2f xv = {cur[q].z, cur[q].w};
                    aA0 = __builtin_elementwise_fma(xu, v2f{wA[q].x, wA[q].y}, aA0);
                    aA1 = __builtin_elementwise_fma(xv, v2f{wA[q].z, wA[q].w}, aA1);
                    aB0 = __builtin_elementwise_fma(xu, v2f{wB[q].x, wB[q].y}, aB0);
                    aB1 = __builtin_elementwise_fma(xv, v2f{wB[q].z, wB[q].w}, aB1);
                }
                float pA = (aA0.x + aA0.y) + (aA1.x + aA1.y);
                float pB = (aB0.x + aB0.y) + (aB1.x + aB1.y);
                ring[s & 3][u * 64 + lane] = float2{pA, pB};
                #pragma unroll
                for (int q = 0; q < FINQ; ++q) cur[q] = nxt[q];
            }
            __syncthreads();
        }
    } else {
        // ---------------- consumer ----------------
        const int u  = wv - 2;
        const int rA = u * 128 + lane;
        const int rB = u * 128 + 64 + lane;
        float4 hA[16], hB[16];
        #pragma unroll
        for (int q = 0; q < 16; ++q) hA[q] = Whh4[rA * 16 + q];
        #pragma unroll
        for (int q = 0; q < 16; ++q) hB[q] = Whh4[rB * 16 + q];

        float hs[64];                    // uniform after readlane -> SGPR-class
        #pragma unroll
        for (int k = 0; k < 64; ++k) hs[k] = 0.0f;

        float c = 0.f, hl = 0.f;
        float pMyA = 0.f, pMyB = 0.f;    // my pre-act pair from previous step
        float* hrow = STORE_H ? (hout + (size_t)b * Tsz * Hd) : nullptr;

        #pragma unroll 1
        for (int s = 0; s < Tsz + 3; ++s) {
            const int th = s - 3;        // time whose h we finish now
            const int tp = s - 2;        // time whose pre-act we produce now
            if (th >= 0) {
                float2 other = exch[(s - 1) & 1][(1 - u) * 64 + lane];
                float pi, pf, pg, po;
                if (u == 0) { pi = pMyA; pf = pMyB; pg = other.x; po = other.y; }
                else        { pg = pMyA; po = pMyB; pi = other.x; pf = other.y; }
                float gi = fsig(pi), gf = fsig(pf), gg = ftanh(pg), go = fsig(po);
                c  = gf * c + gi * gg;
                hl = go * ftanh(c);
                if (STORE_H && u == 0) hrow[th * Hd + lane] = hl;
                #pragma unroll
                for (int k = 0; k < 64; ++k) hs[k] = rlane(hl, k);
            }
            if (tp >= 0 && tp < Tsz) {
                v2f aA0 = {0.f, 0.f}, aA1 = {0.f, 0.f};
                v2f aB0 = {0.f, 0.f}, aB1 = {0.f, 0.f};
                #pragma unroll
                for (int q = 0; q < 16; ++q) {
                    v2f h0 = {hs[4 * q + 0], hs[4 * q + 1]};
                    v2f h1 = {hs[4 * q + 2], hs[4 * q + 3]};
                    aA0 = __builtin_elementwise_fma(h0, v2f{hA[q].x, hA[q].y}, aA0);
                    aA1 = __builtin_elementwise_fma(h1, v2f{hA[q].z, hA[q].w}, aA1);
                    aB0 = __builtin_elementwise_fma(h0, v2f{hB[q].x, hB[q].y}, aB0);
                    aB1 = __builtin_elementwise_fma(h1, v2f{hB[q].z, hB[q].w}, aB1);
                }
                float2 rg = ring[tp & 3][u * 64 + lane];
                pMyA = rg.x + (aA0.x + aA0.y) + (aA1.x + aA1.y);
                pMyB = rg.y + (aB0.x + aB0.y) + (aB1.x + aB1.y);
                exch[s & 1][u * 64 + lane] = float2{pMyA, pMyB};
            }
            __syncthreads();
        }

        if (DO_FC && u == 0) {
            float p = hl * fcW[lane];
            #pragma unroll
            for (int off = 32; off > 0; off >>= 1) p += __shfl_down(p, off);
            if (lane == 0) out[b] = p + fcb[0];
        }
    }
}

extern "C" void kernel_launch(void* const* d_in, const int* in_sizes, int n_in,
                              void* d_out, int out_size, void* d_ws, size_t ws_size,
                              hipStream_t stream)
{
    const float* x    = (const float*)d_in[0];
    const float* Wih0 = (const float*)d_in[1];
    const float* Whh0 = (const float*)d_in[2];
    const float* bih0 = (const float*)d_in[3];
    const float* bhh0 = (const float*)d_in[4];
    const float* Wih1 = (const float*)d_in[5];
    const float* Whh1 = (const float*)d_in[6];
    const float* bih1 = (const float*)d_in[7];
    const float* bhh1 = (const float*)d_in[8];
    const float* fcW  = (const float*)d_in[9];
    const float* fcb  = (const float*)d_in[10];
    float* out = (float*)d_out;
    float* h1  = (float*)d_ws; // B*T*H fp32 = 64 MB scratch

    lstm_layer<8, true, false><<<dim3(Bsz), dim3(256), 0, stream>>>(
        x, (const float4*)Wih0, (const float4*)Whh0, bih0, bhh0, h1,
        nullptr, nullptr, nullptr);
    lstm_layer<16, false, true><<<dim3(Bsz), dim3(256), 0, stream>>>(
        h1, (const float4*)Wih1, (const float4*)Whh1, bih1, bhh1, nullptr,
        fcW, fcb, out);
}

// Round 5
// 947.527 us; speedup vs baseline: 1.3017x; 1.3017x over previous
//
#include <hip/hip_runtime.h>
#include <math.h>

#define Bsz 512
#define Tsz 512
#define Hd 64
#define CH 16
#define NCH (Tsz / CH)

typedef float v2f __attribute__((ext_vector_type(2)));

__device__ __forceinline__ float fsig(float x){ return 1.0f/(1.0f+__expf(-x)); }
__device__ __forceinline__ float ftanh(float x){
    float ax=fabsf(x); float e=__expf(-2.0f*ax);
    float t=(1.0f-e)/(1.0f+e); return copysignf(t,x);
}
__device__ __forceinline__ float rlane(float v, int k){
    return __int_as_float(__builtin_amdgcn_readlane(__float_as_int(v), k));
}

// 2 waves per batch row, chunk-decoupled producer/consumer:
//  wave0 (producer): computes pre-gates {i,f,g,o} for a whole CH-step chunk into a
//    double-buffered LDS buffer. x is staged 2 chunks deep (global->regs->LDS),
//    so HBM latency is amortized over ~8000 cyc of chunk compute. Reads x via
//    wave-uniform ds_read_b128 (broadcast), owns all 4 gate rows of its lane.
//  wave1 (consumer): serial recurrence, NO barriers inside a chunk. Owns all 4
//    gate rows of h-element `lane` (Whh in regs), h broadcast via 64 readlane ->
//    SGPRs (VALU pipe, no LDS datapath, no latency gap). Barriers: NCH+1 total.

template<int KQ, bool STORE_H, bool DO_FC>
__global__ __launch_bounds__(128, 1)
void lstm_layer(const float* __restrict__ xin,    // [B, T, KQ*4]
                const float4* __restrict__ Wih4,  // [256, KQ]
                const float4* __restrict__ Whh4,  // [256, 16]
                const float* __restrict__ bih, const float* __restrict__ bhh,
                float* __restrict__ hout,         // [B, T, 64] if STORE_H
                const float* __restrict__ fcW, const float* __restrict__ fcb,
                float* __restrict__ out)          // [B] if DO_FC
{
    __shared__ float4 pre[2][CH * 64];   // [parity][t*64 + l] = {pi,pf,pg,po}
    __shared__ float4 xst[2][CH * KQ];   // x chunks (producer-private dbuf)

    const int lane = threadIdx.x & 63;
    const int wv   = threadIdx.x >> 6;
    const int b    = blockIdx.x;

    if (wv == 0) {
        // ---------------- producer ----------------
        float4 w[4][KQ];
        float  bb[4];
        #pragma unroll
        for (int g = 0; g < 4; ++g) {
            const int row = g * 64 + lane;
            #pragma unroll
            for (int q = 0; q < KQ; ++q) w[g][q] = Wih4[row * KQ + q];
            bb[g] = bih[row] + bhh[row];
        }
        const float4* xg = (const float4*)(xin + (size_t)b * Tsz * (KQ * 4));
        constexpr int LD = (CH * KQ) / 64;   // float4 per lane per chunk
        float4 ld[LD];

        // prologue: stage chunks 0 and 1, compute pre[0]
        #pragma unroll
        for (int i = 0; i < LD; ++i) ld[i] = xg[0 * CH * KQ + i * 64 + lane];
        #pragma unroll
        for (int i = 0; i < LD; ++i) xst[0][i * 64 + lane] = ld[i];
        #pragma unroll
        for (int i = 0; i < LD; ++i) ld[i] = xg[1 * CH * KQ + i * 64 + lane];
        #pragma unroll
        for (int i = 0; i < LD; ++i) xst[1][i * 64 + lane] = ld[i];

        #pragma unroll 1
        for (int t = 0; t < CH; ++t) {   // chunk 0 -> pre[0]
            const float4* xrow = (const float4*)&xst[0][t * KQ];
            v2f a0[4], a1[4];
            #pragma unroll
            for (int g = 0; g < 4; ++g) { a0[g] = v2f{bb[g], 0.f}; a1[g] = v2f{0.f, 0.f}; }
            #pragma unroll
            for (int q = 0; q < KQ; ++q) {
                float4 xq = xrow[q];
                v2f xu = {xq.x, xq.y}, xv = {xq.z, xq.w};
                #pragma unroll
                for (int g = 0; g < 4; ++g) {
                    a0[g] = __builtin_elementwise_fma(xu, v2f{w[g][q].x, w[g][q].y}, a0[g]);
                    a1[g] = __builtin_elementwise_fma(xv, v2f{w[g][q].z, w[g][q].w}, a1[g]);
                }
            }
            float4 p;
            p.x = (a0[0].x + a0[0].y) + (a1[0].x + a1[0].y);
            p.y = (a0[1].x + a0[1].y) + (a1[1].x + a1[1].y);
            p.z = (a0[2].x + a0[2].y) + (a1[2].x + a1[2].y);
            p.w = (a0[3].x + a0[3].y) + (a1[3].x + a1[3].y);
            pre[0][t * 64 + lane] = p;
        }
        __syncthreads();   // pre[0] ready

        #pragma unroll 1
        for (int c = 0; c < NCH; ++c) {
            if (c + 1 < NCH) {
                const bool more = (c + 2 < NCH);
                if (more) {
                    #pragma unroll
                    for (int i = 0; i < LD; ++i)
                        ld[i] = xg[(c + 2) * CH * KQ + i * 64 + lane];
                }
                const int pb = (c + 1) & 1;
                #pragma unroll 1
                for (int t = 0; t < CH; ++t) {    // chunk c+1 -> pre[pb] from xst[pb]
                    const float4* xrow = (const float4*)&xst[pb][t * KQ];
                    v2f a0[4], a1[4];
                    #pragma unroll
                    for (int g = 0; g < 4; ++g) { a0[g] = v2f{bb[g], 0.f}; a1[g] = v2f{0.f, 0.f}; }
                    #pragma unroll
                    for (int q = 0; q < KQ; ++q) {
                        float4 xq = xrow[q];
                        v2f xu = {xq.x, xq.y}, xv = {xq.z, xq.w};
                        #pragma unroll
                        for (int g = 0; g < 4; ++g) {
                            a0[g] = __builtin_elementwise_fma(xu, v2f{w[g][q].x, w[g][q].y}, a0[g]);
                            a1[g] = __builtin_elementwise_fma(xv, v2f{w[g][q].z, w[g][q].w}, a1[g]);
                        }
                    }
                    float4 p;
                    p.x = (a0[0].x + a0[0].y) + (a1[0].x + a1[0].y);
                    p.y = (a0[1].x + a0[1].y) + (a1[1].x + a1[1].y);
                    p.z = (a0[2].x + a0[2].y) + (a1[2].x + a1[2].y);
                    p.w = (a0[3].x + a0[3].y) + (a1[3].x + a1[3].y);
                    pre[pb][t * 64 + lane] = p;
                }
                if (more) {
                    #pragma unroll
                    for (int i = 0; i < LD; ++i) xst[c & 1][i * 64 + lane] = ld[i];
                }
            }
            __syncthreads();
        }
    } else {
        // ---------------- consumer ----------------
        float4 wh[4][16];
        #pragma unroll
        for (int g = 0; g < 4; ++g) {
            const int row = g * 64 + lane;
            #pragma unroll
            for (int q = 0; q < 16; ++q) wh[g][q] = Whh4[row * 16 + q];
        }
        v2f hs[32];
        #pragma unroll
        for (int k = 0; k < 32; ++k) hs[k] = v2f{0.f, 0.f};
        float cc = 0.f, hl = 0.f;
        float* hrow = STORE_H ? (hout + (size_t)b * Tsz * Hd) : nullptr;

        __syncthreads();   // wait for pre[0]

        #pragma unroll 1
        for (int c = 0; c < NCH; ++c) {
            const float4* pb = &pre[c & 1][0];
            float4 pg = pb[lane];   // prefetch t=0 of this chunk
            #pragma unroll 1
            for (int t = 0; t < CH; ++t) {
                float4 pcur = pg;
                if (t + 1 < CH) pg = pb[(t + 1) * 64 + lane];   // prefetch next step
                v2f a0[4], a1[4];
                #pragma unroll
                for (int g = 0; g < 4; ++g) { a0[g] = v2f{0.f, 0.f}; a1[g] = v2f{0.f, 0.f}; }
                #pragma unroll
                for (int q = 0; q < 16; ++q) {
                    v2f h0 = hs[2 * q], h1 = hs[2 * q + 1];
                    #pragma unroll
                    for (int g = 0; g < 4; ++g) {
                        a0[g] = __builtin_elementwise_fma(h0, v2f{wh[g][q].x, wh[g][q].y}, a0[g]);
                        a1[g] = __builtin_elementwise_fma(h1, v2f{wh[g][q].z, wh[g][q].w}, a1[g]);
                    }
                }
                float pi = pcur.x + (a0[0].x + a0[0].y) + (a1[0].x + a1[0].y);
                float pf = pcur.y + (a0[1].x + a0[1].y) + (a1[1].x + a1[1].y);
                float pgg= pcur.z + (a0[2].x + a0[2].y) + (a1[2].x + a1[2].y);
                float po = pcur.w + (a0[3].x + a0[3].y) + (a1[3].x + a1[3].y);
                float gi = fsig(pi), gf = fsig(pf), gg = ftanh(pgg), go = fsig(po);
                cc = gf * cc + gi * gg;
                hl = go * ftanh(cc);
                if (STORE_H) hrow[(c * CH + t) * Hd + lane] = hl;
                #pragma unroll
                for (int k = 0; k < 32; ++k) {
                    hs[k].x = rlane(hl, 2 * k);
                    hs[k].y = rlane(hl, 2 * k + 1);
                }
            }
            __syncthreads();
        }

        if (DO_FC) {
            float p = hl * fcW[lane];
            #pragma unroll
            for (int off = 32; off > 0; off >>= 1) p += __shfl_down(p, off);
            if (lane == 0) out[b] = p + fcb[0];
        }
    }
}

extern "C" void kernel_launch(void* const* d_in, const int* in_sizes, int n_in,
                              void* d_out, int out_size, void* d_ws, size_t ws_size,
                              hipStream_t stream)
{
    const float* x    = (const float*)d_in[0];
    const float* Wih0 = (const float*)d_in[1];
    const float* Whh0 = (const float*)d_in[2];
    const float* bih0 = (const float*)d_in[3];
    const float* bhh0 = (const float*)d_in[4];
    const float* Wih1 = (const float*)d_in[5];
    const float* Whh1 = (const float*)d_in[6];
    const float* bih1 = (const float*)d_in[7];
    const float* bhh1 = (const float*)d_in[8];
    const float* fcW  = (const float*)d_in[9];
    const float* fcb  = (const float*)d_in[10];
    float* out = (float*)d_out;
    float* h1  = (float*)d_ws;   // B*T*H fp32 = 64 MB scratch

    lstm_layer<8, true, false><<<dim3(Bsz), dim3(128), 0, stream>>>(
        x, (const float4*)Wih0, (const float4*)Whh0, bih0, bhh0, h1,
        nullptr, nullptr, nullptr);
    lstm_layer<16, false, true><<<dim3(Bsz), dim3(128), 0, stream>>>(
        h1, (const float4*)Wih1, (const float4*)Whh1, bih1, bhh1, nullptr,
        fcW, fcb, out);
}